// Round 7
// baseline (142.925 us; speedup 1.0000x reference)
//
#include <hip/hip_runtime.h>

typedef short bf16x8 __attribute__((ext_vector_type(8)));
typedef float f32x4 __attribute__((ext_vector_type(4)));

static __device__ __forceinline__ unsigned short f2bf(float f) {
  unsigned u = __builtin_bit_cast(unsigned, f);
  u += 0x7FFFu + ((u >> 16) & 1u);   // round-nearest-even to bf16
  return (unsigned short)(u >> 16);
}

static __device__ __forceinline__ bf16x8 pack8(const float* p) {
  float4 a = *(const float4*)p;
  float4 b = *(const float4*)(p + 4);
  bf16x8 r;
  r[0] = (short)f2bf(a.x); r[1] = (short)f2bf(a.y);
  r[2] = (short)f2bf(a.z); r[3] = (short)f2bf(a.w);
  r[4] = (short)f2bf(b.x); r[5] = (short)f2bf(b.y);
  r[6] = (short)f2bf(b.z); r[7] = (short)f2bf(b.w);
  return r;
}

// ---------------- LayerNorm: x[B,C,H,W] f32 -> xn[B,H,W,C] bf16 ----------------
__global__ __launch_bounds__(256) void ln_kernel(
    const float* __restrict__ x, const float* __restrict__ lg,
    const float* __restrict__ lb, unsigned short* __restrict__ xn) {
  __shared__ float tile[128][65];
  __shared__ float ps[8][64];
  __shared__ float mu_s[64], rs_s[64];
  const int bid = blockIdx.x;
  const int b = bid >> 6, h = bid & 63;
  const int tid = threadIdx.x;
  const int w = tid & 63, cq = tid >> 6;
  const float* xp = x + ((size_t)(b * 128) * 64 + h) * 64 + w;
  float s1 = 0.f, s2 = 0.f;
#pragma unroll
  for (int c = cq; c < 128; c += 4) {
    float v = xp[(size_t)c * 4096];
    tile[c][w] = v;
    s1 += v; s2 += v * v;
  }
  ps[cq][w] = s1; ps[4 + cq][w] = s2;
  __syncthreads();
  if (tid < 64) {
    float a1 = ps[0][tid] + ps[1][tid] + ps[2][tid] + ps[3][tid];
    float a2 = ps[4][tid] + ps[5][tid] + ps[6][tid] + ps[7][tid];
    float mu = a1 * 0.0078125f;
    float var = a2 * 0.0078125f - mu * mu;
    mu_s[tid] = mu;
    rs_s[tid] = rsqrtf(var + 1e-5f);
  }
  __syncthreads();
  const int lane = tid & 63, w4 = tid >> 6;
  const int c0 = lane * 2;
  const float g0 = lg[c0], g1 = lg[c0 + 1], b0 = lb[c0], b1 = lb[c0 + 1];
#pragma unroll
  for (int w2 = w4; w2 < 64; w2 += 4) {
    const float mu = mu_s[w2], rs = rs_s[w2];
    float y0 = (tile[c0][w2] - mu) * rs * g0 + b0;
    float y1 = (tile[c0 + 1][w2] - mu) * rs * g1 + b1;
    unsigned pk = (unsigned)f2bf(y0) | ((unsigned)f2bf(y1) << 16);
    *(unsigned*)((unsigned char*)xn + ((size_t)((b * 64 + h) * 64 + w2)) * 256 + c0 * 2) = pk;
  }
}

// ---------------- Persistent bidirectional GRU scan ----------------
// grid = 4 dirs * 64 groups; block = 512 (8 waves); 16 sequences per block.
// W is the MFMA A operand, x/h tile is B; D[m=gatecol][n=seq].
// x staged in LDS, double-buffered; during step t we ALSO read xa(t+1) and
// compute the x-gate MFMAs for step t+1 (look-ahead), so the post-barrier
// critical chain is only ha-read -> 12 depth-4 h-MFMAs -> gate math -> h write.
// Hazards: every LDS buffer's reads and writes are separated by one barrier:
//   xbufA: written even step (x(t+2)), read odd step (xa);  xbufB: converse.
// LDS: xbufA @0, xbufB @4096, hbufA @8192, hbufB @12288 (full-row XOR swizzle).
__global__ __launch_bounds__(512, 2) void scan_kernel(
    const unsigned short* __restrict__ xn, unsigned short* __restrict__ cat,
    const float* __restrict__ wih0, const float* __restrict__ whh0,
    const float* __restrict__ bih0, const float* __restrict__ bhh0,
    const float* __restrict__ wih1, const float* __restrict__ whh1,
    const float* __restrict__ bih1, const float* __restrict__ bhh1,
    const float* __restrict__ wih2, const float* __restrict__ whh2,
    const float* __restrict__ bih2, const float* __restrict__ bhh2,
    const float* __restrict__ wih3, const float* __restrict__ whh3,
    const float* __restrict__ bih3, const float* __restrict__ bhh3) {
  __shared__ __align__(16) unsigned char lds[16384];
  const int tid = threadIdx.x;
  const int bid = blockIdx.x;
  const int dir = bid >> 6;
  const int grp = bid & 63;
  const int fwd = !(dir & 1);
  const int vert = dir >> 1;
  const int b = grp >> 2;
  const int r0 = (grp & 3) << 4;
  const int wv = tid >> 6;
  const int lane = tid & 63;
  const int l15 = lane & 15;
  const int l4 = lane >> 4;

  const float* wih = dir == 0 ? wih0 : dir == 1 ? wih1 : dir == 2 ? wih2 : wih3;
  const float* whh = dir == 0 ? whh0 : dir == 1 ? whh1 : dir == 2 ? whh2 : whh3;
  const float* bih = dir == 0 ? bih0 : dir == 1 ? bih1 : dir == 2 ? bih2 : bih3;
  const float* bhh = dir == 0 ? bhh0 : dir == 1 ? bhh1 : dir == 2 ? bhh2 : bhh3;

  // A-fragments (weights): lane's m-row = gatecol wv*16 + l15, k = kc*32+l4*8+0..7
  const int ca = (wv << 4) + l15;
  bf16x8 wf[3][2][4];
#pragma unroll
  for (int g = 0; g < 3; ++g) {
#pragma unroll
    for (int s = 0; s < 2; ++s) {
      const float* Wp = s ? whh : wih;
#pragma unroll
      for (int kc = 0; kc < 4; ++kc)
        wf[g][s][kc] = pack8(Wp + (size_t)((g << 7) + ca) * 128 + (kc << 5) + (l4 << 3));
    }
  }
  // Biases: 4 consecutive channels per lane (c = wv*16 + l4*4 + 0..3).
  const int cb = (wv << 4) + (l4 << 2);
  f32x4 br4, bz4, bnx4, bnh4;
  {
    float4 a = *(const float4*)(bih + cb), b2 = *(const float4*)(bhh + cb);
    br4[0] = a.x + b2.x; br4[1] = a.y + b2.y; br4[2] = a.z + b2.z; br4[3] = a.w + b2.w;
    a = *(const float4*)(bih + 128 + cb); b2 = *(const float4*)(bhh + 128 + cb);
    bz4[0] = a.x + b2.x; bz4[1] = a.y + b2.y; bz4[2] = a.z + b2.z; bz4[3] = a.w + b2.w;
    a = *(const float4*)(bih + 256 + cb);
    bnx4[0] = a.x; bnx4[1] = a.y; bnx4[2] = a.z; bnx4[3] = a.w;
    b2 = *(const float4*)(bhh + 256 + cb);
    bnh4[0] = b2.x; bnh4[1] = b2.y; bnh4[2] = b2.z; bnh4[3] = b2.w;
  }

  // Staging geometry: threads 0..255 own (row ss, 16B chunk ck).
  const int ss = tid >> 4, ck = tid & 15;
  const unsigned char* xsp =
      (const unsigned char*)xn +
      (vert ? ((size_t)b << 20) + (size_t)(r0 + ss) * 256 + (ck << 4)
            : ((size_t)(b * 64 + r0 + ss) << 14) + (ck << 4));
  const int xstep = vert ? 16384 : 256;
  const int sdst = (ss * 256 + (ck << 4)) ^ ((ss & 15) << 4);

  // Per-lane cat store pointer (incremental).
  const int seq = r0 + l15;
  const int cstep = vert ? 65536 : 1024;
  unsigned char* catp =
      (unsigned char*)cat +
      ((size_t)b * 4096 + (size_t)(vert ? seq : seq * 64)) * 1024 + dir * 256 + (cb << 1) +
      (size_t)(fwd ? 0 : 63) * cstep;
  const int cdelta = fwd ? cstep : -cstep;

  // zero hbufA (@8192, 4KB)
  *(unsigned long long*)(lds + 8192 + tid * 8) = 0ull;
  f32x4 hst = {0.f, 0.f, 0.f, 0.f};

  // Prologue: per-lane gather of x(t0) fragments -> xg(0); stage x(t1) into
  // xbufB; preload x(t2) into sX.
  uint4 sX, sY;
  f32x4 grA, gzA, gnxA, grB, gzB, gnxB;
  {
    const unsigned char* xlq =
        (const unsigned char*)xn +
        (vert ? ((size_t)b << 20) + (size_t)(fwd ? 0 : 63) * 16384 + (size_t)seq * 256
              : ((size_t)(b * 64 + seq) << 14) + (size_t)(fwd ? 0 : 63) * 256) +
        (l4 << 4);
    bf16x8 x0[4];
#pragma unroll
    for (int kc = 0; kc < 4; ++kc) x0[kc] = *(const bf16x8*)(xlq + (kc << 6));
    uint4 s1v;
    if (tid < 256) {
      s1v = *(const uint4*)(xsp + (fwd ? 1 : 62) * xstep);
      sX = *(const uint4*)(xsp + (fwd ? 2 : 61) * xstep);
    }
    grA = br4; gzA = bz4; gnxA = bnx4;
#pragma unroll
    for (int kc = 0; kc < 4; ++kc) {
      grA = __builtin_amdgcn_mfma_f32_16x16x32_bf16(wf[0][0][kc], x0[kc], grA, 0, 0, 0);
      gzA = __builtin_amdgcn_mfma_f32_16x16x32_bf16(wf[1][0][kc], x0[kc], gzA, 0, 0, 0);
      gnxA = __builtin_amdgcn_mfma_f32_16x16x32_bf16(wf[2][0][kc], x0[kc], gnxA, 0, 0, 0);
    }
    if (tid < 256) *(uint4*)(lds + 4096 + sdst) = s1v;
  }
  __syncthreads();  // hbufA zero + xbufB(x(t1)) visible

#define STEP(TT, HCUR, HNXT, XRD, XWR, XW, XL, GRC, GZC, GNXC, GRN, GZN, GNXN)  \
  {                                                                             \
    bf16x8 ha[4], xa[4];                                                        \
    _Pragma("unroll")                                                           \
    for (int kc = 0; kc < 4; ++kc) {                                            \
      const int base = (l15 * 256 + (kc << 6) + (l4 << 4)) ^ (l15 << 4);        \
      ha[kc] = *(const bf16x8*)(lds + (HCUR) + base);                           \
      xa[kc] = *(const bf16x8*)(lds + (XRD) + base);                            \
    }                                                                           \
    if (tid < 256) {                                                            \
      *(uint4*)(lds + (XWR) + sdst) = XW;                                       \
      const int tl = (TT) + 3 > 63 ? 63 : (TT) + 3;                             \
      XL = *(const uint4*)(xsp + (fwd ? tl : 63 - tl) * xstep);                 \
    }                                                                           \
    /* h chains: three independent depth-4 (critical) */                       \
    f32x4 rh = {0.f, 0.f, 0.f, 0.f}, zh = {0.f, 0.f, 0.f, 0.f}, nh = bnh4;     \
    _Pragma("unroll")                                                           \
    for (int kc = 0; kc < 4; ++kc) {                                            \
      rh = __builtin_amdgcn_mfma_f32_16x16x32_bf16(wf[0][1][kc], ha[kc], rh, 0, 0, 0); \
      zh = __builtin_amdgcn_mfma_f32_16x16x32_bf16(wf[1][1][kc], ha[kc], zh, 0, 0, 0); \
      nh = __builtin_amdgcn_mfma_f32_16x16x32_bf16(wf[2][1][kc], ha[kc], nh, 0, 0, 0); \
    }                                                                           \
    /* x-gate look-ahead for step TT+1 (off the critical chain) */              \
    GRN = br4; GZN = bz4; GNXN = bnx4;                                          \
    _Pragma("unroll")                                                           \
    for (int kc = 0; kc < 4; ++kc) {                                            \
      GRN = __builtin_amdgcn_mfma_f32_16x16x32_bf16(wf[0][0][kc], xa[kc], GRN, 0, 0, 0); \
      GZN = __builtin_amdgcn_mfma_f32_16x16x32_bf16(wf[1][0][kc], xa[kc], GZN, 0, 0, 0); \
      GNXN = __builtin_amdgcn_mfma_f32_16x16x32_bf16(wf[2][0][kc], xa[kc], GNXN, 0, 0, 0); \
    }                                                                           \
    f32x4 hnew;                                                                 \
    _Pragma("unroll")                                                           \
    for (int r = 0; r < 4; ++r) {                                               \
      const float rr = __builtin_amdgcn_rcpf(1.f + __expf(-(GRC[r] + rh[r]))); \
      const float zz = __builtin_amdgcn_rcpf(1.f + __expf(-(GZC[r] + zh[r]))); \
      const float pre = GNXC[r] + rr * nh[r];                                   \
      const float e2 = __expf(-2.f * pre);                                      \
      const float nn = fmaf(2.f, __builtin_amdgcn_rcpf(1.f + e2), -1.f);        \
      hnew[r] = nn + zz * (hst[r] - nn);                                        \
    }                                                                           \
    hst = hnew;                                                                 \
    unsigned hp0, hp1;                                                          \
    asm("v_cvt_pk_bf16_f32 %0, %1, %2" : "=v"(hp0) : "v"(hnew[0]), "v"(hnew[1])); \
    asm("v_cvt_pk_bf16_f32 %0, %1, %2" : "=v"(hp1) : "v"(hnew[2]), "v"(hnew[3])); \
    {                                                                           \
      unsigned long long hp = (unsigned long long)hp0 | ((unsigned long long)hp1 << 32); \
      *(unsigned long long*)(lds + (HNXT) + ((l15 * 256 + (cb << 1)) ^ (l15 << 4))) = hp; \
    }                                                                           \
    {                                                                           \
      uint2 v; v.x = hp0; v.y = hp1;                                            \
      *(uint2*)catp = v;                                                        \
      catp += cdelta;                                                           \
    }                                                                           \
    asm volatile("s_waitcnt lgkmcnt(0)" ::: "memory");                          \
    __builtin_amdgcn_s_barrier();                                               \
    asm volatile("" ::: "memory");                                              \
  }

  for (int tt2 = 0; tt2 < 64; tt2 += 2) {
    STEP(tt2, 8192, 12288, 4096, 0, sX, sY, grA, gzA, gnxA, grB, gzB, gnxB);
    STEP(tt2 + 1, 12288, 8192, 0, 4096, sY, sX, grB, gzB, gnxB, grA, gzA, gnxA);
  }
#undef STEP
}

// ---------------- Projection: out = cat[65536,512] @ pw^T + pb + x, -> [B,C,HW] ----------------
__global__ __launch_bounds__(256, 2) void proj_kernel(
    const unsigned short* __restrict__ cat, const float* __restrict__ pw,
    const float* __restrict__ pb, const float* __restrict__ x,
    float* __restrict__ out) {
  __shared__ __align__(16) unsigned char at[65536];
  const int tid = threadIdx.x;
  const int bid = blockIdx.x;
  const int row0 = bid << 6;
  const int b = row0 >> 12;
  const int hw0 = row0 & 4095;
  const int wv = tid >> 6, lane = tid & 63, l15 = lane & 15, l4 = lane >> 4;

#pragma unroll
  for (int it = 0; it < 16; ++it) {
    const int item = tid + (it << 8);
    const int rr = item >> 6, ckk = item & 63;
    uint4 v = *(const uint4*)((const unsigned char*)cat +
                              ((size_t)(row0 + rr)) * 1024 + ckk * 16);
    *(uint4*)(at + rr * 1024 + ((ckk ^ (rr & 7)) << 4)) = v;
  }

  bf16x8 wfr[2][16];
  float pbv[2];
#pragma unroll
  for (int ct = 0; ct < 2; ++ct) {
    const int cc = (wv << 5) + (ct << 4) + l15;
    pbv[ct] = pb[cc];
#pragma unroll
    for (int kc = 0; kc < 16; ++kc)
      wfr[ct][kc] = pack8(pw + (size_t)cc * 512 + (kc << 5) + (l4 << 3));
  }
  __syncthreads();

  f32x4 acc[4][2];
#pragma unroll
  for (int mt = 0; mt < 4; ++mt) {
    acc[mt][0] = {pbv[0], pbv[0], pbv[0], pbv[0]};
    acc[mt][1] = {pbv[1], pbv[1], pbv[1], pbv[1]};
  }
#pragma unroll
  for (int mt = 0; mt < 4; ++mt) {
    const int rr = (mt << 4) + l15;
#pragma unroll
    for (int kc = 0; kc < 16; ++kc) {
      bf16x8 af =
          *(const bf16x8*)(at + rr * 1024 + ((((kc << 2) + l4) ^ (rr & 7)) << 4));
      acc[mt][0] = __builtin_amdgcn_mfma_f32_16x16x32_bf16(af, wfr[0][kc], acc[mt][0], 0, 0, 0);
      acc[mt][1] = __builtin_amdgcn_mfma_f32_16x16x32_bf16(af, wfr[1][kc], acc[mt][1], 0, 0, 0);
    }
  }

  // Epilogue: transpose via LDS so out/x traffic is fully coalesced.
  // ldsT[c][hw] f32, pitch 68 floats (272B, keeps b128 stores 16B-aligned).
  __syncthreads();  // all MFMA reads of at[] done
#pragma unroll
  for (int mt = 0; mt < 4; ++mt) {
#pragma unroll
    for (int ct = 0; ct < 2; ++ct) {
      const int cc = (wv << 5) + (ct << 4) + l15;
      *(f32x4*)(at + cc * 272 + (mt << 6) + (l4 << 4)) = acc[mt][ct];
    }
  }
  __syncthreads();
#pragma unroll
  for (int it = 0; it < 32; ++it) {
    const int c = (wv << 5) + it;
    const float v = *(const float*)(at + c * 272 + lane * 4);
    const size_t off = (size_t)(b * 128 + c) * 4096 + hw0 + lane;
    out[off] = v + x[off];
  }
}

extern "C" void kernel_launch(void* const* d_in, const int* in_sizes, int n_in,
                              void* d_out, int out_size, void* d_ws, size_t ws_size,
                              hipStream_t stream) {
  const float* x = (const float*)d_in[0];
  const float* lg = (const float*)d_in[1];
  const float* lb = (const float*)d_in[2];
  unsigned short* xn = (unsigned short*)d_ws;  // [16][64][64][128] bf16 = 16.8MB
  unsigned short* cat =
      (unsigned short*)((unsigned char*)d_ws + (size_t)16 * 64 * 64 * 128 * 2);  // [65536][512] bf16 = 67MB

  ln_kernel<<<1024, 256, 0, stream>>>(x, lg, lb, xn);
  scan_kernel<<<256, 512, 0, stream>>>(
      xn, cat,
      (const float*)d_in[3], (const float*)d_in[4], (const float*)d_in[5], (const float*)d_in[6],
      (const float*)d_in[7], (const float*)d_in[8], (const float*)d_in[9], (const float*)d_in[10],
      (const float*)d_in[11], (const float*)d_in[12], (const float*)d_in[13], (const float*)d_in[14],
      (const float*)d_in[15], (const float*)d_in[16], (const float*)d_in[17], (const float*)d_in[18]);
  proj_kernel<<<1024, 256, 0, stream>>>(cat, (const float*)d_in[19], (const float*)d_in[20], x,
                                        (float*)d_out);
}

// Round 8
// 130.893 us; speedup vs baseline: 1.0919x; 1.0919x over previous
//
#include <hip/hip_runtime.h>

typedef short bf16x8 __attribute__((ext_vector_type(8)));
typedef float f32x4 __attribute__((ext_vector_type(4)));

static __device__ __forceinline__ unsigned short f2bf(float f) {
  unsigned u = __builtin_bit_cast(unsigned, f);
  u += 0x7FFFu + ((u >> 16) & 1u);   // round-nearest-even to bf16
  return (unsigned short)(u >> 16);
}

static __device__ __forceinline__ bf16x8 pack8(const float* p) {
  float4 a = *(const float4*)p;
  float4 b = *(const float4*)(p + 4);
  bf16x8 r;
  r[0] = (short)f2bf(a.x); r[1] = (short)f2bf(a.y);
  r[2] = (short)f2bf(a.z); r[3] = (short)f2bf(a.w);
  r[4] = (short)f2bf(b.x); r[5] = (short)f2bf(b.y);
  r[6] = (short)f2bf(b.z); r[7] = (short)f2bf(b.w);
  return r;
}

// ---------------- pw f32[128][512] -> bf16 (one-time) ----------------
__global__ __launch_bounds__(512) void pwprep_kernel(
    const float* __restrict__ pw, unsigned short* __restrict__ pwb) {
  const int i = blockIdx.x * 512 + threadIdx.x;
  pwb[i] = f2bf(pw[i]);
}

// ---------------- LayerNorm: x[B,C,H,W] f32 -> xn[B,H,W,C] bf16 ----------------
__global__ __launch_bounds__(256) void ln_kernel(
    const float* __restrict__ x, const float* __restrict__ lg,
    const float* __restrict__ lb, unsigned short* __restrict__ xn) {
  __shared__ float tile[128][65];
  __shared__ float ps[8][64];
  __shared__ float mu_s[64], rs_s[64];
  const int bid = blockIdx.x;
  const int b = bid >> 6, h = bid & 63;
  const int tid = threadIdx.x;
  const int w = tid & 63, cq = tid >> 6;
  const float* xp = x + ((size_t)(b * 128) * 64 + h) * 64 + w;
  float s1 = 0.f, s2 = 0.f;
#pragma unroll
  for (int c = cq; c < 128; c += 4) {
    float v = xp[(size_t)c * 4096];
    tile[c][w] = v;
    s1 += v; s2 += v * v;
  }
  ps[cq][w] = s1; ps[4 + cq][w] = s2;
  __syncthreads();
  if (tid < 64) {
    float a1 = ps[0][tid] + ps[1][tid] + ps[2][tid] + ps[3][tid];
    float a2 = ps[4][tid] + ps[5][tid] + ps[6][tid] + ps[7][tid];
    float mu = a1 * 0.0078125f;
    float var = a2 * 0.0078125f - mu * mu;
    mu_s[tid] = mu;
    rs_s[tid] = rsqrtf(var + 1e-5f);
  }
  __syncthreads();
  const int lane = tid & 63, w4 = tid >> 6;
  const int c0 = lane * 2;
  const float g0 = lg[c0], g1 = lg[c0 + 1], b0 = lb[c0], b1 = lb[c0 + 1];
#pragma unroll
  for (int w2 = w4; w2 < 64; w2 += 4) {
    const float mu = mu_s[w2], rs = rs_s[w2];
    float y0 = (tile[c0][w2] - mu) * rs * g0 + b0;
    float y1 = (tile[c0 + 1][w2] - mu) * rs * g1 + b1;
    unsigned pk = (unsigned)f2bf(y0) | ((unsigned)f2bf(y1) << 16);
    *(unsigned*)((unsigned char*)xn + ((size_t)((b * 64 + h) * 64 + w2)) * 256 + c0 * 2) = pk;
  }
}

// ---------------- Persistent bidirectional GRU scan ----------------
// Same structure as round 7 (75 µs best); gate math now pairs the r/z
// reciprocals (one v_rcp for both sigmoids): 24 -> 20 trans ops/lane/step.
__global__ __launch_bounds__(512, 2) void scan_kernel(
    const unsigned short* __restrict__ xn, unsigned short* __restrict__ cat,
    const float* __restrict__ wih0, const float* __restrict__ whh0,
    const float* __restrict__ bih0, const float* __restrict__ bhh0,
    const float* __restrict__ wih1, const float* __restrict__ whh1,
    const float* __restrict__ bih1, const float* __restrict__ bhh1,
    const float* __restrict__ wih2, const float* __restrict__ whh2,
    const float* __restrict__ bih2, const float* __restrict__ bhh2,
    const float* __restrict__ wih3, const float* __restrict__ whh3,
    const float* __restrict__ bih3, const float* __restrict__ bhh3) {
  __shared__ __align__(16) unsigned char lds[16384];
  const int tid = threadIdx.x;
  const int bid = blockIdx.x;
  const int dir = bid >> 6;
  const int grp = bid & 63;
  const int fwd = !(dir & 1);
  const int vert = dir >> 1;
  const int b = grp >> 2;
  const int r0 = (grp & 3) << 4;
  const int wv = tid >> 6;
  const int lane = tid & 63;
  const int l15 = lane & 15;
  const int l4 = lane >> 4;

  const float* wih = dir == 0 ? wih0 : dir == 1 ? wih1 : dir == 2 ? wih2 : wih3;
  const float* whh = dir == 0 ? whh0 : dir == 1 ? whh1 : dir == 2 ? whh2 : whh3;
  const float* bih = dir == 0 ? bih0 : dir == 1 ? bih1 : dir == 2 ? bih2 : bih3;
  const float* bhh = dir == 0 ? bhh0 : dir == 1 ? bhh1 : dir == 2 ? bhh2 : bhh3;

  const int ca = (wv << 4) + l15;
  bf16x8 wf[3][2][4];
#pragma unroll
  for (int g = 0; g < 3; ++g) {
#pragma unroll
    for (int s = 0; s < 2; ++s) {
      const float* Wp = s ? whh : wih;
#pragma unroll
      for (int kc = 0; kc < 4; ++kc)
        wf[g][s][kc] = pack8(Wp + (size_t)((g << 7) + ca) * 128 + (kc << 5) + (l4 << 3));
    }
  }
  const int cb = (wv << 4) + (l4 << 2);
  f32x4 br4, bz4, bnx4, bnh4;
  {
    float4 a = *(const float4*)(bih + cb), b2 = *(const float4*)(bhh + cb);
    br4[0] = a.x + b2.x; br4[1] = a.y + b2.y; br4[2] = a.z + b2.z; br4[3] = a.w + b2.w;
    a = *(const float4*)(bih + 128 + cb); b2 = *(const float4*)(bhh + 128 + cb);
    bz4[0] = a.x + b2.x; bz4[1] = a.y + b2.y; bz4[2] = a.z + b2.z; bz4[3] = a.w + b2.w;
    a = *(const float4*)(bih + 256 + cb);
    bnx4[0] = a.x; bnx4[1] = a.y; bnx4[2] = a.z; bnx4[3] = a.w;
    b2 = *(const float4*)(bhh + 256 + cb);
    bnh4[0] = b2.x; bnh4[1] = b2.y; bnh4[2] = b2.z; bnh4[3] = b2.w;
  }

  const int ss = tid >> 4, ck = tid & 15;
  const unsigned char* xsp =
      (const unsigned char*)xn +
      (vert ? ((size_t)b << 20) + (size_t)(r0 + ss) * 256 + (ck << 4)
            : ((size_t)(b * 64 + r0 + ss) << 14) + (ck << 4));
  const int xstep = vert ? 16384 : 256;
  const int sdst = (ss * 256 + (ck << 4)) ^ ((ss & 15) << 4);

  const int seq = r0 + l15;
  const int cstep = vert ? 65536 : 1024;
  unsigned char* catp =
      (unsigned char*)cat +
      ((size_t)b * 4096 + (size_t)(vert ? seq : seq * 64)) * 1024 + dir * 256 + (cb << 1) +
      (size_t)(fwd ? 0 : 63) * cstep;
  const int cdelta = fwd ? cstep : -cstep;

  *(unsigned long long*)(lds + 8192 + tid * 8) = 0ull;
  f32x4 hst = {0.f, 0.f, 0.f, 0.f};

  uint4 sX, sY;
  f32x4 grA, gzA, gnxA, grB, gzB, gnxB;
  {
    const unsigned char* xlq =
        (const unsigned char*)xn +
        (vert ? ((size_t)b << 20) + (size_t)(fwd ? 0 : 63) * 16384 + (size_t)seq * 256
              : ((size_t)(b * 64 + seq) << 14) + (size_t)(fwd ? 0 : 63) * 256) +
        (l4 << 4);
    bf16x8 x0[4];
#pragma unroll
    for (int kc = 0; kc < 4; ++kc) x0[kc] = *(const bf16x8*)(xlq + (kc << 6));
    uint4 s1v;
    if (tid < 256) {
      s1v = *(const uint4*)(xsp + (fwd ? 1 : 62) * xstep);
      sX = *(const uint4*)(xsp + (fwd ? 2 : 61) * xstep);
    }
    grA = br4; gzA = bz4; gnxA = bnx4;
#pragma unroll
    for (int kc = 0; kc < 4; ++kc) {
      grA = __builtin_amdgcn_mfma_f32_16x16x32_bf16(wf[0][0][kc], x0[kc], grA, 0, 0, 0);
      gzA = __builtin_amdgcn_mfma_f32_16x16x32_bf16(wf[1][0][kc], x0[kc], gzA, 0, 0, 0);
      gnxA = __builtin_amdgcn_mfma_f32_16x16x32_bf16(wf[2][0][kc], x0[kc], gnxA, 0, 0, 0);
    }
    if (tid < 256) *(uint4*)(lds + 4096 + sdst) = s1v;
  }
  __syncthreads();

#define STEP(TT, HCUR, HNXT, XRD, XWR, XW, XL, GRC, GZC, GNXC, GRN, GZN, GNXN)  \
  {                                                                             \
    bf16x8 ha[4], xa[4];                                                        \
    _Pragma("unroll")                                                           \
    for (int kc = 0; kc < 4; ++kc) {                                            \
      const int base = (l15 * 256 + (kc << 6) + (l4 << 4)) ^ (l15 << 4);        \
      ha[kc] = *(const bf16x8*)(lds + (HCUR) + base);                           \
      xa[kc] = *(const bf16x8*)(lds + (XRD) + base);                            \
    }                                                                           \
    if (tid < 256) {                                                            \
      *(uint4*)(lds + (XWR) + sdst) = XW;                                       \
      const int tl = (TT) + 3 > 63 ? 63 : (TT) + 3;                             \
      XL = *(const uint4*)(xsp + (fwd ? tl : 63 - tl) * xstep);                 \
    }                                                                           \
    f32x4 rh = {0.f, 0.f, 0.f, 0.f}, zh = {0.f, 0.f, 0.f, 0.f}, nh = bnh4;     \
    _Pragma("unroll")                                                           \
    for (int kc = 0; kc < 4; ++kc) {                                            \
      rh = __builtin_amdgcn_mfma_f32_16x16x32_bf16(wf[0][1][kc], ha[kc], rh, 0, 0, 0); \
      zh = __builtin_amdgcn_mfma_f32_16x16x32_bf16(wf[1][1][kc], ha[kc], zh, 0, 0, 0); \
      nh = __builtin_amdgcn_mfma_f32_16x16x32_bf16(wf[2][1][kc], ha[kc], nh, 0, 0, 0); \
    }                                                                           \
    GRN = br4; GZN = bz4; GNXN = bnx4;                                          \
    _Pragma("unroll")                                                           \
    for (int kc = 0; kc < 4; ++kc) {                                            \
      GRN = __builtin_amdgcn_mfma_f32_16x16x32_bf16(wf[0][0][kc], xa[kc], GRN, 0, 0, 0); \
      GZN = __builtin_amdgcn_mfma_f32_16x16x32_bf16(wf[1][0][kc], xa[kc], GZN, 0, 0, 0); \
      GNXN = __builtin_amdgcn_mfma_f32_16x16x32_bf16(wf[2][0][kc], xa[kc], GNXN, 0, 0, 0); \
    }                                                                           \
    f32x4 hnew;                                                                 \
    _Pragma("unroll")                                                           \
    for (int r = 0; r < 4; ++r) {                                               \
      const float er = __expf(-(GRC[r] + rh[r]));                               \
      const float ez = __expf(-(GZC[r] + zh[r]));                               \
      const float P = 1.f + er, Q = 1.f + ez;                                   \
      const float inv = __builtin_amdgcn_rcpf(P * Q);                           \
      const float rr = Q * inv;                                                 \
      const float zz = P * inv;                                                 \
      const float pre = GNXC[r] + rr * nh[r];                                   \
      const float e2 = __expf(-2.f * pre);                                      \
      const float i2 = __builtin_amdgcn_rcpf(1.f + e2);                         \
      const float nn = (1.f - e2) * i2;                                         \
      hnew[r] = nn + zz * (hst[r] - nn);                                        \
    }                                                                           \
    hst = hnew;                                                                 \
    unsigned hp0, hp1;                                                          \
    asm("v_cvt_pk_bf16_f32 %0, %1, %2" : "=v"(hp0) : "v"(hnew[0]), "v"(hnew[1])); \
    asm("v_cvt_pk_bf16_f32 %0, %1, %2" : "=v"(hp1) : "v"(hnew[2]), "v"(hnew[3])); \
    {                                                                           \
      unsigned long long hp = (unsigned long long)hp0 | ((unsigned long long)hp1 << 32); \
      *(unsigned long long*)(lds + (HNXT) + ((l15 * 256 + (cb << 1)) ^ (l15 << 4))) = hp; \
    }                                                                           \
    {                                                                           \
      uint2 v; v.x = hp0; v.y = hp1;                                            \
      *(uint2*)catp = v;                                                        \
      catp += cdelta;                                                           \
    }                                                                           \
    asm volatile("s_waitcnt lgkmcnt(0)" ::: "memory");                          \
    __builtin_amdgcn_s_barrier();                                               \
    asm volatile("" ::: "memory");                                              \
  }

  for (int tt2 = 0; tt2 < 64; tt2 += 2) {
    STEP(tt2, 8192, 12288, 4096, 0, sX, sY, grA, gzA, gnxA, grB, gzB, gnxB);
    STEP(tt2 + 1, 12288, 8192, 0, 4096, sY, sX, grB, gzB, gnxB, grA, gzA, gnxA);
  }
#undef STEP
}

// ---------------- Projection: out = cat[65536,512] @ pwb^T + pb + x ----------------
// 512 threads (8 waves), each wave owns 16 output channels (wfr = 64 VGPR).
// cat staged in two 32-row stages (32 KB); epilogue transpose tile pitch 260B
// (bank-conflict-free). Total LDS 33.3 KB, VGPR<=128 -> 4 blocks/CU.
__global__ __launch_bounds__(512, 4) void proj_kernel(
    const unsigned short* __restrict__ cat, const unsigned short* __restrict__ pwb,
    const float* __restrict__ pb, const float* __restrict__ x,
    float* __restrict__ out) {
  __shared__ __align__(16) unsigned char lds[33280];
  const int tid = threadIdx.x;
  const int bid = blockIdx.x;
  const int row0 = bid << 6;
  const int b = row0 >> 12;
  const int hw0 = row0 & 4095;
  const int wv = tid >> 6, lane = tid & 63, l15 = lane & 15, l4 = lane >> 4;

  // B-fragments: lane's n-col = cc, k = kc*32 + l4*8 + 0..7 (bf16 direct).
  const int cc = (wv << 4) + l15;
  bf16x8 wfr[16];
#pragma unroll
  for (int kc = 0; kc < 16; ++kc)
    wfr[kc] = *(const bf16x8*)(pwb + (size_t)cc * 512 + (kc << 5) + (l4 << 3));
  const float pbv = pb[cc];

  f32x4 acc[4];
#pragma unroll
  for (int mt = 0; mt < 4; ++mt) acc[mt] = {pbv, pbv, pbv, pbv};

#pragma unroll
  for (int s = 0; s < 2; ++s) {
    // stage rows s*32 .. s*32+31 (32 KB)
#pragma unroll
    for (int it = 0; it < 4; ++it) {
      const int item = tid + (it << 9);
      const int rr = item >> 6, ckk = item & 63;
      uint4 v = *(const uint4*)((const unsigned char*)cat +
                                ((size_t)(row0 + (s << 5) + rr)) * 1024 + ckk * 16);
      *(uint4*)(lds + rr * 1024 + ((ckk ^ (rr & 7)) << 4)) = v;
    }
    __syncthreads();
#pragma unroll
    for (int mh = 0; mh < 2; ++mh) {
      const int mt = (s << 1) + mh;
      const int rl = (mh << 4) + l15;  // local row in stage
#pragma unroll
      for (int kc = 0; kc < 16; ++kc) {
        bf16x8 af =
            *(const bf16x8*)(lds + rl * 1024 + ((((kc << 2) + l4) ^ (rl & 7)) << 4));
        acc[mt] = __builtin_amdgcn_mfma_f32_16x16x32_bf16(af, wfr[kc], acc[mt], 0, 0, 0);
      }
    }
    __syncthreads();
  }

  // Transpose epilogue: tr[c][hw] f32, pitch 260 B (65 floats: bank step 1).
#pragma unroll
  for (int mt = 0; mt < 4; ++mt)
#pragma unroll
    for (int j = 0; j < 4; ++j)
      *(float*)(lds + cc * 260 + (((mt << 4) + (l4 << 2) + j) << 2)) = acc[mt][j];
  __syncthreads();
#pragma unroll
  for (int it = 0; it < 16; ++it) {
    const int c = (wv << 4) + it;
    const float v = *(const float*)(lds + c * 260 + (lane << 2));
    const size_t off = (size_t)(b * 128 + c) * 4096 + hw0 + lane;
    out[off] = v + x[off];
  }
}

extern "C" void kernel_launch(void* const* d_in, const int* in_sizes, int n_in,
                              void* d_out, int out_size, void* d_ws, size_t ws_size,
                              hipStream_t stream) {
  const float* x = (const float*)d_in[0];
  const float* lg = (const float*)d_in[1];
  const float* lb = (const float*)d_in[2];
  unsigned short* xn = (unsigned short*)d_ws;                       // 16.8 MB
  unsigned short* cat =
      (unsigned short*)((unsigned char*)d_ws + 16777216);           // 67.1 MB
  unsigned short* pwb =
      (unsigned short*)((unsigned char*)d_ws + 16777216 + 67108864);  // 128 KB

  pwprep_kernel<<<128, 512, 0, stream>>>((const float*)d_in[19], pwb);
  ln_kernel<<<1024, 256, 0, stream>>>(x, lg, lb, xn);
  scan_kernel<<<256, 512, 0, stream>>>(
      xn, cat,
      (const float*)d_in[3], (const float*)d_in[4], (const float*)d_in[5], (const float*)d_in[6],
      (const float*)d_in[7], (const float*)d_in[8], (const float*)d_in[9], (const float*)d_in[10],
      (const float*)d_in[11], (const float*)d_in[12], (const float*)d_in[13], (const float*)d_in[14],
      (const float*)d_in[15], (const float*)d_in[16], (const float*)d_in[17], (const float*)d_in[18]);
  proj_kernel<<<1024, 512, 0, stream>>>(cat, pwb, (const float*)d_in[20], x,
                                        (float*)d_out);
}

// Round 9
// 126.534 us; speedup vs baseline: 1.1295x; 1.0345x over previous
//
#include <hip/hip_runtime.h>

typedef short bf16x8 __attribute__((ext_vector_type(8)));
typedef float f32x4 __attribute__((ext_vector_type(4)));

static __device__ __forceinline__ unsigned short f2bf(float f) {
  unsigned u = __builtin_bit_cast(unsigned, f);
  u += 0x7FFFu + ((u >> 16) & 1u);   // round-nearest-even to bf16
  return (unsigned short)(u >> 16);
}

static __device__ __forceinline__ bf16x8 pack8(const float* p) {
  float4 a = *(const float4*)p;
  float4 b = *(const float4*)(p + 4);
  bf16x8 r;
  r[0] = (short)f2bf(a.x); r[1] = (short)f2bf(a.y);
  r[2] = (short)f2bf(a.z); r[3] = (short)f2bf(a.w);
  r[4] = (short)f2bf(b.x); r[5] = (short)f2bf(b.y);
  r[6] = (short)f2bf(b.z); r[7] = (short)f2bf(b.w);
  return r;
}

// ---------------- pw f32[128][512] -> bf16 (one-time) ----------------
__global__ __launch_bounds__(512) void pwprep_kernel(
    const float* __restrict__ pw, unsigned short* __restrict__ pwb) {
  const int i = blockIdx.x * 512 + threadIdx.x;
  pwb[i] = f2bf(pw[i]);
}

// ---------------- LayerNorm: x[B,C,H,W] f32 -> xn[B,H,W,C] bf16 ----------------
__global__ __launch_bounds__(256) void ln_kernel(
    const float* __restrict__ x, const float* __restrict__ lg,
    const float* __restrict__ lb, unsigned short* __restrict__ xn) {
  __shared__ float tile[128][65];
  __shared__ float ps[8][64];
  __shared__ float mu_s[64], rs_s[64];
  const int bid = blockIdx.x;
  const int b = bid >> 6, h = bid & 63;
  const int tid = threadIdx.x;
  const int w = tid & 63, cq = tid >> 6;
  const float* xp = x + ((size_t)(b * 128) * 64 + h) * 64 + w;
  float s1 = 0.f, s2 = 0.f;
#pragma unroll
  for (int c = cq; c < 128; c += 4) {
    float v = xp[(size_t)c * 4096];
    tile[c][w] = v;
    s1 += v; s2 += v * v;
  }
  ps[cq][w] = s1; ps[4 + cq][w] = s2;
  __syncthreads();
  if (tid < 64) {
    float a1 = ps[0][tid] + ps[1][tid] + ps[2][tid] + ps[3][tid];
    float a2 = ps[4][tid] + ps[5][tid] + ps[6][tid] + ps[7][tid];
    float mu = a1 * 0.0078125f;
    float var = a2 * 0.0078125f - mu * mu;
    mu_s[tid] = mu;
    rs_s[tid] = rsqrtf(var + 1e-5f);
  }
  __syncthreads();
  const int lane = tid & 63, w4 = tid >> 6;
  const int c0 = lane * 2;
  const float g0 = lg[c0], g1 = lg[c0 + 1], b0 = lb[c0], b1 = lb[c0 + 1];
#pragma unroll
  for (int w2 = w4; w2 < 64; w2 += 4) {
    const float mu = mu_s[w2], rs = rs_s[w2];
    float y0 = (tile[c0][w2] - mu) * rs * g0 + b0;
    float y1 = (tile[c0 + 1][w2] - mu) * rs * g1 + b1;
    unsigned pk = (unsigned)f2bf(y0) | ((unsigned)f2bf(y1) << 16);
    *(unsigned*)((unsigned char*)xn + ((size_t)((b * 64 + h) * 64 + w2)) * 256 + c0 * 2) = pk;
  }
}

// ---------------- Persistent bidirectional GRU scan ----------------
// Round-7 structure and gate math (measured best: 75.0 µs). Independent
// exp/rcp chains per sigmoid — chain depth beats op count here (r8 lesson).
__global__ __launch_bounds__(512, 2) void scan_kernel(
    const unsigned short* __restrict__ xn, unsigned short* __restrict__ cat,
    const float* __restrict__ wih0, const float* __restrict__ whh0,
    const float* __restrict__ bih0, const float* __restrict__ bhh0,
    const float* __restrict__ wih1, const float* __restrict__ whh1,
    const float* __restrict__ bih1, const float* __restrict__ bhh1,
    const float* __restrict__ wih2, const float* __restrict__ whh2,
    const float* __restrict__ bih2, const float* __restrict__ bhh2,
    const float* __restrict__ wih3, const float* __restrict__ whh3,
    const float* __restrict__ bih3, const float* __restrict__ bhh3) {
  __shared__ __align__(16) unsigned char lds[16384];
  const int tid = threadIdx.x;
  const int bid = blockIdx.x;
  const int dir = bid >> 6;
  const int grp = bid & 63;
  const int fwd = !(dir & 1);
  const int vert = dir >> 1;
  const int b = grp >> 2;
  const int r0 = (grp & 3) << 4;
  const int wv = tid >> 6;
  const int lane = tid & 63;
  const int l15 = lane & 15;
  const int l4 = lane >> 4;

  const float* wih = dir == 0 ? wih0 : dir == 1 ? wih1 : dir == 2 ? wih2 : wih3;
  const float* whh = dir == 0 ? whh0 : dir == 1 ? whh1 : dir == 2 ? whh2 : whh3;
  const float* bih = dir == 0 ? bih0 : dir == 1 ? bih1 : dir == 2 ? bih2 : bih3;
  const float* bhh = dir == 0 ? bhh0 : dir == 1 ? bhh1 : dir == 2 ? bhh2 : bhh3;

  const int ca = (wv << 4) + l15;
  bf16x8 wf[3][2][4];
#pragma unroll
  for (int g = 0; g < 3; ++g) {
#pragma unroll
    for (int s = 0; s < 2; ++s) {
      const float* Wp = s ? whh : wih;
#pragma unroll
      for (int kc = 0; kc < 4; ++kc)
        wf[g][s][kc] = pack8(Wp + (size_t)((g << 7) + ca) * 128 + (kc << 5) + (l4 << 3));
    }
  }
  const int cb = (wv << 4) + (l4 << 2);
  f32x4 br4, bz4, bnx4, bnh4;
  {
    float4 a = *(const float4*)(bih + cb), b2 = *(const float4*)(bhh + cb);
    br4[0] = a.x + b2.x; br4[1] = a.y + b2.y; br4[2] = a.z + b2.z; br4[3] = a.w + b2.w;
    a = *(const float4*)(bih + 128 + cb); b2 = *(const float4*)(bhh + 128 + cb);
    bz4[0] = a.x + b2.x; bz4[1] = a.y + b2.y; bz4[2] = a.z + b2.z; bz4[3] = a.w + b2.w;
    a = *(const float4*)(bih + 256 + cb);
    bnx4[0] = a.x; bnx4[1] = a.y; bnx4[2] = a.z; bnx4[3] = a.w;
    b2 = *(const float4*)(bhh + 256 + cb);
    bnh4[0] = b2.x; bnh4[1] = b2.y; bnh4[2] = b2.z; bnh4[3] = b2.w;
  }

  const int ss = tid >> 4, ck = tid & 15;
  const unsigned char* xsp =
      (const unsigned char*)xn +
      (vert ? ((size_t)b << 20) + (size_t)(r0 + ss) * 256 + (ck << 4)
            : ((size_t)(b * 64 + r0 + ss) << 14) + (ck << 4));
  const int xstep = vert ? 16384 : 256;
  const int sdst = (ss * 256 + (ck << 4)) ^ ((ss & 15) << 4);

  const int seq = r0 + l15;
  const int cstep = vert ? 65536 : 1024;
  unsigned char* catp =
      (unsigned char*)cat +
      ((size_t)b * 4096 + (size_t)(vert ? seq : seq * 64)) * 1024 + dir * 256 + (cb << 1) +
      (size_t)(fwd ? 0 : 63) * cstep;
  const int cdelta = fwd ? cstep : -cstep;

  *(unsigned long long*)(lds + 8192 + tid * 8) = 0ull;
  f32x4 hst = {0.f, 0.f, 0.f, 0.f};

  uint4 sX, sY;
  f32x4 grA, gzA, gnxA, grB, gzB, gnxB;
  {
    const unsigned char* xlq =
        (const unsigned char*)xn +
        (vert ? ((size_t)b << 20) + (size_t)(fwd ? 0 : 63) * 16384 + (size_t)seq * 256
              : ((size_t)(b * 64 + seq) << 14) + (size_t)(fwd ? 0 : 63) * 256) +
        (l4 << 4);
    bf16x8 x0[4];
#pragma unroll
    for (int kc = 0; kc < 4; ++kc) x0[kc] = *(const bf16x8*)(xlq + (kc << 6));
    uint4 s1v;
    if (tid < 256) {
      s1v = *(const uint4*)(xsp + (fwd ? 1 : 62) * xstep);
      sX = *(const uint4*)(xsp + (fwd ? 2 : 61) * xstep);
    }
    grA = br4; gzA = bz4; gnxA = bnx4;
#pragma unroll
    for (int kc = 0; kc < 4; ++kc) {
      grA = __builtin_amdgcn_mfma_f32_16x16x32_bf16(wf[0][0][kc], x0[kc], grA, 0, 0, 0);
      gzA = __builtin_amdgcn_mfma_f32_16x16x32_bf16(wf[1][0][kc], x0[kc], gzA, 0, 0, 0);
      gnxA = __builtin_amdgcn_mfma_f32_16x16x32_bf16(wf[2][0][kc], x0[kc], gnxA, 0, 0, 0);
    }
    if (tid < 256) *(uint4*)(lds + 4096 + sdst) = s1v;
  }
  __syncthreads();

#define STEP(TT, HCUR, HNXT, XRD, XWR, XW, XL, GRC, GZC, GNXC, GRN, GZN, GNXN)  \
  {                                                                             \
    bf16x8 ha[4], xa[4];                                                        \
    _Pragma("unroll")                                                           \
    for (int kc = 0; kc < 4; ++kc) {                                            \
      const int base = (l15 * 256 + (kc << 6) + (l4 << 4)) ^ (l15 << 4);        \
      ha[kc] = *(const bf16x8*)(lds + (HCUR) + base);                           \
      xa[kc] = *(const bf16x8*)(lds + (XRD) + base);                            \
    }                                                                           \
    if (tid < 256) {                                                            \
      *(uint4*)(lds + (XWR) + sdst) = XW;                                       \
      const int tl = (TT) + 3 > 63 ? 63 : (TT) + 3;                             \
      XL = *(const uint4*)(xsp + (fwd ? tl : 63 - tl) * xstep);                 \
    }                                                                           \
    f32x4 rh = {0.f, 0.f, 0.f, 0.f}, zh = {0.f, 0.f, 0.f, 0.f}, nh = bnh4;     \
    _Pragma("unroll")                                                           \
    for (int kc = 0; kc < 4; ++kc) {                                            \
      rh = __builtin_amdgcn_mfma_f32_16x16x32_bf16(wf[0][1][kc], ha[kc], rh, 0, 0, 0); \
      zh = __builtin_amdgcn_mfma_f32_16x16x32_bf16(wf[1][1][kc], ha[kc], zh, 0, 0, 0); \
      nh = __builtin_amdgcn_mfma_f32_16x16x32_bf16(wf[2][1][kc], ha[kc], nh, 0, 0, 0); \
    }                                                                           \
    GRN = br4; GZN = bz4; GNXN = bnx4;                                          \
    _Pragma("unroll")                                                           \
    for (int kc = 0; kc < 4; ++kc) {                                            \
      GRN = __builtin_amdgcn_mfma_f32_16x16x32_bf16(wf[0][0][kc], xa[kc], GRN, 0, 0, 0); \
      GZN = __builtin_amdgcn_mfma_f32_16x16x32_bf16(wf[1][0][kc], xa[kc], GZN, 0, 0, 0); \
      GNXN = __builtin_amdgcn_mfma_f32_16x16x32_bf16(wf[2][0][kc], xa[kc], GNXN, 0, 0, 0); \
    }                                                                           \
    f32x4 hnew;                                                                 \
    _Pragma("unroll")                                                           \
    for (int r = 0; r < 4; ++r) {                                               \
      const float rr = __builtin_amdgcn_rcpf(1.f + __expf(-(GRC[r] + rh[r]))); \
      const float zz = __builtin_amdgcn_rcpf(1.f + __expf(-(GZC[r] + zh[r]))); \
      const float pre = GNXC[r] + rr * nh[r];                                   \
      const float e2 = __expf(-2.f * pre);                                      \
      const float nn = fmaf(2.f, __builtin_amdgcn_rcpf(1.f + e2), -1.f);        \
      hnew[r] = nn + zz * (hst[r] - nn);                                        \
    }                                                                           \
    hst = hnew;                                                                 \
    unsigned hp0, hp1;                                                          \
    asm("v_cvt_pk_bf16_f32 %0, %1, %2" : "=v"(hp0) : "v"(hnew[0]), "v"(hnew[1])); \
    asm("v_cvt_pk_bf16_f32 %0, %1, %2" : "=v"(hp1) : "v"(hnew[2]), "v"(hnew[3])); \
    {                                                                           \
      unsigned long long hp = (unsigned long long)hp0 | ((unsigned long long)hp1 << 32); \
      *(unsigned long long*)(lds + (HNXT) + ((l15 * 256 + (cb << 1)) ^ (l15 << 4))) = hp; \
    }                                                                           \
    {                                                                           \
      uint2 v; v.x = hp0; v.y = hp1;                                            \
      *(uint2*)catp = v;                                                        \
      catp += cdelta;                                                           \
    }                                                                           \
    asm volatile("s_waitcnt lgkmcnt(0)" ::: "memory");                          \
    __builtin_amdgcn_s_barrier();                                               \
    asm volatile("" ::: "memory");                                              \
  }

  for (int tt2 = 0; tt2 < 64; tt2 += 2) {
    STEP(tt2, 8192, 12288, 4096, 0, sX, sY, grA, gzA, gnxA, grB, gzB, gnxB);
    STEP(tt2 + 1, 12288, 8192, 0, 4096, sY, sX, grB, gzB, gnxB, grA, gzA, gnxA);
  }
#undef STEP
}

// ---------------- Projection: out = cat[65536,512] @ pwb^T + pb + x ----------------
// 512 threads (8 waves), each wave owns 16 output channels (wfr = 64 VGPR).
// cat staged in two 32-row stages (32 KB); epilogue transpose tile pitch 260B
// (bank-conflict-free). Total LDS 33.3 KB, VGPR<=128 -> 4 blocks/CU.
__global__ __launch_bounds__(512, 4) void proj_kernel(
    const unsigned short* __restrict__ cat, const unsigned short* __restrict__ pwb,
    const float* __restrict__ pb, const float* __restrict__ x,
    float* __restrict__ out) {
  __shared__ __align__(16) unsigned char lds[33280];
  const int tid = threadIdx.x;
  const int bid = blockIdx.x;
  const int row0 = bid << 6;
  const int b = row0 >> 12;
  const int hw0 = row0 & 4095;
  const int wv = tid >> 6, lane = tid & 63, l15 = lane & 15, l4 = lane >> 4;

  // B-fragments: lane's n-col = cc, k = kc*32 + l4*8 + 0..7 (bf16 direct).
  const int cc = (wv << 4) + l15;
  bf16x8 wfr[16];
#pragma unroll
  for (int kc = 0; kc < 16; ++kc)
    wfr[kc] = *(const bf16x8*)(pwb + (size_t)cc * 512 + (kc << 5) + (l4 << 3));
  const float pbv = pb[cc];

  f32x4 acc[4];
#pragma unroll
  for (int mt = 0; mt < 4; ++mt) acc[mt] = {pbv, pbv, pbv, pbv};

#pragma unroll
  for (int s = 0; s < 2; ++s) {
    // stage rows s*32 .. s*32+31 (32 KB)
#pragma unroll
    for (int it = 0; it < 4; ++it) {
      const int item = tid + (it << 9);
      const int rr = item >> 6, ckk = item & 63;
      uint4 v = *(const uint4*)((const unsigned char*)cat +
                                ((size_t)(row0 + (s << 5) + rr)) * 1024 + ckk * 16);
      *(uint4*)(lds + rr * 1024 + ((ckk ^ (rr & 7)) << 4)) = v;
    }
    __syncthreads();
#pragma unroll
    for (int mh = 0; mh < 2; ++mh) {
      const int mt = (s << 1) + mh;
      const int rl = (mh << 4) + l15;  // local row in stage
#pragma unroll
      for (int kc = 0; kc < 16; ++kc) {
        bf16x8 af =
            *(const bf16x8*)(lds + rl * 1024 + ((((kc << 2) + l4) ^ (rl & 7)) << 4));
        acc[mt] = __builtin_amdgcn_mfma_f32_16x16x32_bf16(af, wfr[kc], acc[mt], 0, 0, 0);
      }
    }
    __syncthreads();
  }

  // Transpose epilogue: tr[c][hw] f32, pitch 260 B (65 floats: bank step 1).
#pragma unroll
  for (int mt = 0; mt < 4; ++mt)
#pragma unroll
    for (int j = 0; j < 4; ++j)
      *(float*)(lds + cc * 260 + (((mt << 4) + (l4 << 2) + j) << 2)) = acc[mt][j];
  __syncthreads();
#pragma unroll
  for (int it = 0; it < 16; ++it) {
    const int c = (wv << 4) + it;
    const float v = *(const float*)(lds + c * 260 + (lane << 2));
    const size_t off = (size_t)(b * 128 + c) * 4096 + hw0 + lane;
    out[off] = v + x[off];
  }
}

extern "C" void kernel_launch(void* const* d_in, const int* in_sizes, int n_in,
                              void* d_out, int out_size, void* d_ws, size_t ws_size,
                              hipStream_t stream) {
  const float* x = (const float*)d_in[0];
  const float* lg = (const float*)d_in[1];
  const float* lb = (const float*)d_in[2];
  unsigned short* xn = (unsigned short*)d_ws;                       // 16.8 MB
  unsigned short* cat =
      (unsigned short*)((unsigned char*)d_ws + 16777216);           // 67.1 MB
  unsigned short* pwb =
      (unsigned short*)((unsigned char*)d_ws + 16777216 + 67108864);  // 128 KB

  pwprep_kernel<<<128, 512, 0, stream>>>((const float*)d_in[19], pwb);
  ln_kernel<<<1024, 256, 0, stream>>>(x, lg, lb, xn);
  scan_kernel<<<256, 512, 0, stream>>>(
      xn, cat,
      (const float*)d_in[3], (const float*)d_in[4], (const float*)d_in[5], (const float*)d_in[6],
      (const float*)d_in[7], (const float*)d_in[8], (const float*)d_in[9], (const float*)d_in[10],
      (const float*)d_in[11], (const float*)d_in[12], (const float*)d_in[13], (const float*)d_in[14],
      (const float*)d_in[15], (const float*)d_in[16], (const float*)d_in[17], (const float*)d_in[18]);
  proj_kernel<<<1024, 512, 0, stream>>>(cat, pwb, (const float*)d_in[20], x,
                                        (float*)d_out);
}

// Round 10
// 118.756 us; speedup vs baseline: 1.2035x; 1.0655x over previous
//
#include <hip/hip_runtime.h>

typedef short bf16x8 __attribute__((ext_vector_type(8)));
typedef float f32x4 __attribute__((ext_vector_type(4)));

static __device__ __forceinline__ unsigned short f2bf(float f) {
  unsigned u = __builtin_bit_cast(unsigned, f);
  u += 0x7FFFu + ((u >> 16) & 1u);   // round-nearest-even to bf16
  return (unsigned short)(u >> 16);
}

static __device__ __forceinline__ bf16x8 pack8s(const float* p, float s) {
  float4 a = *(const float4*)p;
  float4 b = *(const float4*)(p + 4);
  bf16x8 r;
  r[0] = (short)f2bf(a.x * s); r[1] = (short)f2bf(a.y * s);
  r[2] = (short)f2bf(a.z * s); r[3] = (short)f2bf(a.w * s);
  r[4] = (short)f2bf(b.x * s); r[5] = (short)f2bf(b.y * s);
  r[6] = (short)f2bf(b.z * s); r[7] = (short)f2bf(b.w * s);
  return r;
}

#define NLOG2E -1.442695040888963f
#define N2LOG2E -2.885390081777927f

// ---------------- pw f32[128][512] -> bf16 (one-time) ----------------
__global__ __launch_bounds__(512) void pwprep_kernel(
    const float* __restrict__ pw, unsigned short* __restrict__ pwb) {
  const int i = blockIdx.x * 512 + threadIdx.x;
  pwb[i] = f2bf(pw[i]);
}

// ---------------- LayerNorm: x[B,C,H,W] f32 -> xn[B,HW,C] bf16 ----------------
// 512 blocks (16 b x 32 hw-tiles of 128 positions), 512 threads.
// Thread (q=tid>>5, slot=tid&31) owns channels q*8..q*8+7 x positions
// hw0+slot*4..+3, loaded as float4 (wave = 2x512B contiguous runs).
// Stats in registers -> shfl_xor(32) -> LDS cross-wave reduce. Output packed
// bf16 via a 272B-pitch LDS tile, dumped as 1KB-contiguous uint4 streams.
__global__ __launch_bounds__(512, 2) void ln_kernel(
    const float* __restrict__ x, const float* __restrict__ lg,
    const float* __restrict__ lb, unsigned short* __restrict__ xn) {
  __shared__ __align__(16) unsigned char slds[35840];
  // [0, 34816): phase1-2 = ps[8 waves][32 slots][8] pitch 36B; phase3 = bf16
  // tile [128 pos][272B]. [34816, 35328): mu_s f32[128]; [35328,35840): rs_s.
  float* mu_s = (float*)(slds + 34816);
  float* rs_s = (float*)(slds + 35328);
  const int tid = threadIdx.x;
  const int bid = blockIdx.x;
  const int b = bid >> 5;
  const int hw0 = (bid & 31) << 7;
  const int q = tid >> 5, slot = tid & 31;
  const int lane = tid & 63, wv = tid >> 6;

  const float* xbase = x + ((size_t)b * 128) * 4096 + hw0 + (slot << 2);
  float4 xv[8];
#pragma unroll
  for (int p = 0; p < 8; ++p)
    xv[p] = *(const float4*)(xbase + (size_t)(q * 8 + p) * 4096);

  float s1[4] = {0.f, 0.f, 0.f, 0.f}, s2[4] = {0.f, 0.f, 0.f, 0.f};
#pragma unroll
  for (int p = 0; p < 8; ++p) {
    s1[0] += xv[p].x; s2[0] = fmaf(xv[p].x, xv[p].x, s2[0]);
    s1[1] += xv[p].y; s2[1] = fmaf(xv[p].y, xv[p].y, s2[1]);
    s1[2] += xv[p].z; s2[2] = fmaf(xv[p].z, xv[p].z, s2[2]);
    s1[3] += xv[p].w; s2[3] = fmaf(xv[p].w, xv[p].w, s2[3]);
  }
#pragma unroll
  for (int j = 0; j < 4; ++j) {
    s1[j] += __shfl_xor(s1[j], 32);
    s2[j] += __shfl_xor(s2[j], 32);
  }
  if (lane < 32) {
    float* psp = (float*)(slds + (wv * 32 + slot) * 36);
#pragma unroll
    for (int j = 0; j < 4; ++j) { psp[j] = s1[j]; psp[4 + j] = s2[j]; }
  }
  __syncthreads();
  if (tid < 128) {
    const int sl2 = tid >> 2, j2 = tid & 3;
    float a1 = 0.f, a2 = 0.f;
#pragma unroll
    for (int w = 0; w < 8; ++w) {
      const float* psp = (const float*)(slds + (w * 32 + sl2) * 36);
      a1 += psp[j2]; a2 += psp[4 + j2];
    }
    const float mu = a1 * 0.0078125f;
    const float var = a2 * 0.0078125f - mu * mu;
    mu_s[tid] = mu;
    rs_s[tid] = rsqrtf(var + 1e-5f);
  }
  __syncthreads();

  float lgv[8], lbv[8];
#pragma unroll
  for (int p = 0; p < 8; ++p) { lgv[p] = lg[q * 8 + p]; lbv[p] = lb[q * 8 + p]; }
#pragma unroll
  for (int j = 0; j < 4; ++j) {
    const int pos = (slot << 2) + j;
    const float mu = mu_s[pos], rs = rs_s[pos];
    float y[8];
#pragma unroll
    for (int p = 0; p < 8; ++p) {
      const float xvj = j == 0 ? xv[p].x : j == 1 ? xv[p].y : j == 2 ? xv[p].z : xv[p].w;
      y[p] = (xvj - mu) * rs * lgv[p] + lbv[p];
    }
    unsigned h0, h1, h2, h3;
    asm("v_cvt_pk_bf16_f32 %0, %1, %2" : "=v"(h0) : "v"(y[0]), "v"(y[1]));
    asm("v_cvt_pk_bf16_f32 %0, %1, %2" : "=v"(h1) : "v"(y[2]), "v"(y[3]));
    asm("v_cvt_pk_bf16_f32 %0, %1, %2" : "=v"(h2) : "v"(y[4]), "v"(y[5]));
    asm("v_cvt_pk_bf16_f32 %0, %1, %2" : "=v"(h3) : "v"(y[6]), "v"(y[7]));
    uint4 v; v.x = h0; v.y = h1; v.z = h2; v.w = h3;
    *(uint4*)(slds + pos * 272 + (q << 4)) = v;
  }
  __syncthreads();
#pragma unroll
  for (int it = 0; it < 4; ++it) {
    const int idx = (it << 9) + tid;
    const int row = idx >> 4, g = idx & 15;
    uint4 v = *(const uint4*)(slds + row * 272 + (g << 4));
    *(uint4*)((unsigned char*)xn + ((size_t)(b * 4096 + hw0 + row)) * 256 + (g << 4)) = v;
  }
}

// ---------------- Persistent bidirectional GRU scan ----------------
// Round-7 structure (measured best: 75.0 µs) + exp2 weight-prescale:
// r,z rows x (-log2e), n rows x (-2log2e) folded into the bf16 fragment pack,
// so each sigmoid/tanh uses v_exp directly (no x1.4427 mul, no negate).
__global__ __launch_bounds__(512, 2) void scan_kernel(
    const unsigned short* __restrict__ xn, unsigned short* __restrict__ cat,
    const float* __restrict__ wih0, const float* __restrict__ whh0,
    const float* __restrict__ bih0, const float* __restrict__ bhh0,
    const float* __restrict__ wih1, const float* __restrict__ whh1,
    const float* __restrict__ bih1, const float* __restrict__ bhh1,
    const float* __restrict__ wih2, const float* __restrict__ whh2,
    const float* __restrict__ bih2, const float* __restrict__ bhh2,
    const float* __restrict__ wih3, const float* __restrict__ whh3,
    const float* __restrict__ bih3, const float* __restrict__ bhh3) {
  __shared__ __align__(16) unsigned char lds[16384];
  const int tid = threadIdx.x;
  const int bid = blockIdx.x;
  const int dir = bid >> 6;
  const int grp = bid & 63;
  const int fwd = !(dir & 1);
  const int vert = dir >> 1;
  const int b = grp >> 2;
  const int r0 = (grp & 3) << 4;
  const int wv = tid >> 6;
  const int lane = tid & 63;
  const int l15 = lane & 15;
  const int l4 = lane >> 4;

  const float* wih = dir == 0 ? wih0 : dir == 1 ? wih1 : dir == 2 ? wih2 : wih3;
  const float* whh = dir == 0 ? whh0 : dir == 1 ? whh1 : dir == 2 ? whh2 : whh3;
  const float* bih = dir == 0 ? bih0 : dir == 1 ? bih1 : dir == 2 ? bih2 : bih3;
  const float* bhh = dir == 0 ? bhh0 : dir == 1 ? bhh1 : dir == 2 ? bhh2 : bhh3;

  const int ca = (wv << 4) + l15;
  bf16x8 wf[3][2][4];
#pragma unroll
  for (int g = 0; g < 3; ++g) {
    const float sc = g == 2 ? N2LOG2E : NLOG2E;
#pragma unroll
    for (int s = 0; s < 2; ++s) {
      const float* Wp = s ? whh : wih;
#pragma unroll
      for (int kc = 0; kc < 4; ++kc)
        wf[g][s][kc] = pack8s(Wp + (size_t)((g << 7) + ca) * 128 + (kc << 5) + (l4 << 3), sc);
    }
  }
  const int cb = (wv << 4) + (l4 << 2);
  f32x4 br4, bz4, bnx4, bnh4;
  {
    float4 a = *(const float4*)(bih + cb), b2 = *(const float4*)(bhh + cb);
    br4[0] = (a.x + b2.x) * NLOG2E; br4[1] = (a.y + b2.y) * NLOG2E;
    br4[2] = (a.z + b2.z) * NLOG2E; br4[3] = (a.w + b2.w) * NLOG2E;
    a = *(const float4*)(bih + 128 + cb); b2 = *(const float4*)(bhh + 128 + cb);
    bz4[0] = (a.x + b2.x) * NLOG2E; bz4[1] = (a.y + b2.y) * NLOG2E;
    bz4[2] = (a.z + b2.z) * NLOG2E; bz4[3] = (a.w + b2.w) * NLOG2E;
    a = *(const float4*)(bih + 256 + cb);
    bnx4[0] = a.x * N2LOG2E; bnx4[1] = a.y * N2LOG2E;
    bnx4[2] = a.z * N2LOG2E; bnx4[3] = a.w * N2LOG2E;
    b2 = *(const float4*)(bhh + 256 + cb);
    bnh4[0] = b2.x * N2LOG2E; bnh4[1] = b2.y * N2LOG2E;
    bnh4[2] = b2.z * N2LOG2E; bnh4[3] = b2.w * N2LOG2E;
  }

  const int ss = tid >> 4, ck = tid & 15;
  const unsigned char* xsp =
      (const unsigned char*)xn +
      (vert ? ((size_t)b << 20) + (size_t)(r0 + ss) * 256 + (ck << 4)
            : ((size_t)(b * 64 + r0 + ss) << 14) + (ck << 4));
  const int xstep = vert ? 16384 : 256;
  const int sdst = (ss * 256 + (ck << 4)) ^ ((ss & 15) << 4);

  const int seq = r0 + l15;
  const int cstep = vert ? 65536 : 1024;
  unsigned char* catp =
      (unsigned char*)cat +
      ((size_t)b * 4096 + (size_t)(vert ? seq : seq * 64)) * 1024 + dir * 256 + (cb << 1) +
      (size_t)(fwd ? 0 : 63) * cstep;
  const int cdelta = fwd ? cstep : -cstep;

  *(unsigned long long*)(lds + 8192 + tid * 8) = 0ull;
  f32x4 hst = {0.f, 0.f, 0.f, 0.f};

  uint4 sX, sY;
  f32x4 grA, gzA, gnxA, grB, gzB, gnxB;
  {
    const unsigned char* xlq =
        (const unsigned char*)xn +
        (vert ? ((size_t)b << 20) + (size_t)(fwd ? 0 : 63) * 16384 + (size_t)seq * 256
              : ((size_t)(b * 64 + seq) << 14) + (size_t)(fwd ? 0 : 63) * 256) +
        (l4 << 4);
    bf16x8 x0[4];
#pragma unroll
    for (int kc = 0; kc < 4; ++kc) x0[kc] = *(const bf16x8*)(xlq + (kc << 6));
    uint4 s1v;
    if (tid < 256) {
      s1v = *(const uint4*)(xsp + (fwd ? 1 : 62) * xstep);
      sX = *(const uint4*)(xsp + (fwd ? 2 : 61) * xstep);
    }
    grA = br4; gzA = bz4; gnxA = bnx4;
#pragma unroll
    for (int kc = 0; kc < 4; ++kc) {
      grA = __builtin_amdgcn_mfma_f32_16x16x32_bf16(wf[0][0][kc], x0[kc], grA, 0, 0, 0);
      gzA = __builtin_amdgcn_mfma_f32_16x16x32_bf16(wf[1][0][kc], x0[kc], gzA, 0, 0, 0);
      gnxA = __builtin_amdgcn_mfma_f32_16x16x32_bf16(wf[2][0][kc], x0[kc], gnxA, 0, 0, 0);
    }
    if (tid < 256) *(uint4*)(lds + 4096 + sdst) = s1v;
  }
  __syncthreads();

#define STEP(TT, HCUR, HNXT, XRD, XWR, XW, XL, GRC, GZC, GNXC, GRN, GZN, GNXN)  \
  {                                                                             \
    bf16x8 ha[4], xa[4];                                                        \
    _Pragma("unroll")                                                           \
    for (int kc = 0; kc < 4; ++kc) {                                            \
      const int base = (l15 * 256 + (kc << 6) + (l4 << 4)) ^ (l15 << 4);        \
      ha[kc] = *(const bf16x8*)(lds + (HCUR) + base);                           \
      xa[kc] = *(const bf16x8*)(lds + (XRD) + base);                            \
    }                                                                           \
    if (tid < 256) {                                                            \
      *(uint4*)(lds + (XWR) + sdst) = XW;                                       \
      const int tl = (TT) + 3 > 63 ? 63 : (TT) + 3;                             \
      XL = *(const uint4*)(xsp + (fwd ? tl : 63 - tl) * xstep);                 \
    }                                                                           \
    f32x4 rh = {0.f, 0.f, 0.f, 0.f}, zh = {0.f, 0.f, 0.f, 0.f}, nh = bnh4;     \
    _Pragma("unroll")                                                           \
    for (int kc = 0; kc < 4; ++kc) {                                            \
      rh = __builtin_amdgcn_mfma_f32_16x16x32_bf16(wf[0][1][kc], ha[kc], rh, 0, 0, 0); \
      zh = __builtin_amdgcn_mfma_f32_16x16x32_bf16(wf[1][1][kc], ha[kc], zh, 0, 0, 0); \
      nh = __builtin_amdgcn_mfma_f32_16x16x32_bf16(wf[2][1][kc], ha[kc], nh, 0, 0, 0); \
    }                                                                           \
    GRN = br4; GZN = bz4; GNXN = bnx4;                                          \
    _Pragma("unroll")                                                           \
    for (int kc = 0; kc < 4; ++kc) {                                            \
      GRN = __builtin_amdgcn_mfma_f32_16x16x32_bf16(wf[0][0][kc], xa[kc], GRN, 0, 0, 0); \
      GZN = __builtin_amdgcn_mfma_f32_16x16x32_bf16(wf[1][0][kc], xa[kc], GZN, 0, 0, 0); \
      GNXN = __builtin_amdgcn_mfma_f32_16x16x32_bf16(wf[2][0][kc], xa[kc], GNXN, 0, 0, 0); \
    }                                                                           \
    f32x4 hnew;                                                                 \
    _Pragma("unroll")                                                           \
    for (int r = 0; r < 4; ++r) {                                               \
      const float er = __builtin_amdgcn_exp2f(GRC[r] + rh[r]);                  \
      const float rr = __builtin_amdgcn_rcpf(1.f + er);                         \
      const float ez = __builtin_amdgcn_exp2f(GZC[r] + zh[r]);                  \
      const float zz = __builtin_amdgcn_rcpf(1.f + ez);                         \
      const float pre = GNXC[r] + rr * nh[r];                                   \
      const float e2 = __builtin_amdgcn_exp2f(pre);                             \
      const float nn = fmaf(2.f, __builtin_amdgcn_rcpf(1.f + e2), -1.f);        \
      hnew[r] = nn + zz * (hst[r] - nn);                                        \
    }                                                                           \
    hst = hnew;                                                                 \
    unsigned hp0, hp1;                                                          \
    asm("v_cvt_pk_bf16_f32 %0, %1, %2" : "=v"(hp0) : "v"(hnew[0]), "v"(hnew[1])); \
    asm("v_cvt_pk_bf16_f32 %0, %1, %2" : "=v"(hp1) : "v"(hnew[2]), "v"(hnew[3])); \
    {                                                                           \
      unsigned long long hp = (unsigned long long)hp0 | ((unsigned long long)hp1 << 32); \
      *(unsigned long long*)(lds + (HNXT) + ((l15 * 256 + (cb << 1)) ^ (l15 << 4))) = hp; \
    }                                                                           \
    {                                                                           \
      uint2 v; v.x = hp0; v.y = hp1;                                            \
      *(uint2*)catp = v;                                                        \
      catp += cdelta;                                                           \
    }                                                                           \
    asm volatile("s_waitcnt lgkmcnt(0)" ::: "memory");                          \
    __builtin_amdgcn_s_barrier();                                               \
    asm volatile("" ::: "memory");                                              \
  }

  for (int tt2 = 0; tt2 < 64; tt2 += 2) {
    STEP(tt2, 8192, 12288, 4096, 0, sX, sY, grA, gzA, gnxA, grB, gzB, gnxB);
    STEP(tt2 + 1, 12288, 8192, 0, 4096, sY, sX, grB, gzB, gnxB, grA, gzA, gnxA);
  }
#undef STEP
}

// ---------------- Projection: out = cat[65536,512] @ pwb^T + pb + x ----------------
__global__ __launch_bounds__(512, 4) void proj_kernel(
    const unsigned short* __restrict__ cat, const unsigned short* __restrict__ pwb,
    const float* __restrict__ pb, const float* __restrict__ x,
    float* __restrict__ out) {
  __shared__ __align__(16) unsigned char lds[33280];
  const int tid = threadIdx.x;
  const int bid = blockIdx.x;
  const int row0 = bid << 6;
  const int b = row0 >> 12;
  const int hw0 = row0 & 4095;
  const int wv = tid >> 6, lane = tid & 63, l15 = lane & 15, l4 = lane >> 4;

  const int cc = (wv << 4) + l15;
  bf16x8 wfr[16];
#pragma unroll
  for (int kc = 0; kc < 16; ++kc)
    wfr[kc] = *(const bf16x8*)(pwb + (size_t)cc * 512 + (kc << 5) + (l4 << 3));
  const float pbv = pb[cc];

  f32x4 acc[4];
#pragma unroll
  for (int mt = 0; mt < 4; ++mt) acc[mt] = {pbv, pbv, pbv, pbv};

#pragma unroll
  for (int s = 0; s < 2; ++s) {
#pragma unroll
    for (int it = 0; it < 4; ++it) {
      const int item = tid + (it << 9);
      const int rr = item >> 6, ckk = item & 63;
      uint4 v = *(const uint4*)((const unsigned char*)cat +
                                ((size_t)(row0 + (s << 5) + rr)) * 1024 + ckk * 16);
      *(uint4*)(lds + rr * 1024 + ((ckk ^ (rr & 7)) << 4)) = v;
    }
    __syncthreads();
#pragma unroll
    for (int mh = 0; mh < 2; ++mh) {
      const int mt = (s << 1) + mh;
      const int rl = (mh << 4) + l15;
#pragma unroll
      for (int kc = 0; kc < 16; ++kc) {
        bf16x8 af =
            *(const bf16x8*)(lds + rl * 1024 + ((((kc << 2) + l4) ^ (rl & 7)) << 4));
        acc[mt] = __builtin_amdgcn_mfma_f32_16x16x32_bf16(af, wfr[kc], acc[mt], 0, 0, 0);
      }
    }
    __syncthreads();
  }

#pragma unroll
  for (int mt = 0; mt < 4; ++mt)
#pragma unroll
    for (int j = 0; j < 4; ++j)
      *(float*)(lds + cc * 260 + (((mt << 4) + (l4 << 2) + j) << 2)) = acc[mt][j];
  __syncthreads();
#pragma unroll
  for (int it = 0; it < 16; ++it) {
    const int c = (wv << 4) + it;
    const float v = *(const float*)(lds + c * 260 + (lane << 2));
    const size_t off = (size_t)(b * 128 + c) * 4096 + hw0 + lane;
    out[off] = v + x[off];
  }
}

extern "C" void kernel_launch(void* const* d_in, const int* in_sizes, int n_in,
                              void* d_out, int out_size, void* d_ws, size_t ws_size,
                              hipStream_t stream) {
  const float* x = (const float*)d_in[0];
  const float* lg = (const float*)d_in[1];
  const float* lb = (const float*)d_in[2];
  unsigned short* xn = (unsigned short*)d_ws;                       // 16.8 MB
  unsigned short* cat =
      (unsigned short*)((unsigned char*)d_ws + 16777216);           // 67.1 MB
  unsigned short* pwb =
      (unsigned short*)((unsigned char*)d_ws + 16777216 + 67108864);  // 128 KB

  pwprep_kernel<<<128, 512, 0, stream>>>((const float*)d_in[19], pwb);
  ln_kernel<<<512, 512, 0, stream>>>(x, lg, lb, xn);
  scan_kernel<<<256, 512, 0, stream>>>(
      xn, cat,
      (const float*)d_in[3], (const float*)d_in[4], (const float*)d_in[5], (const float*)d_in[6],
      (const float*)d_in[7], (const float*)d_in[8], (const float*)d_in[9], (const float*)d_in[10],
      (const float*)d_in[11], (const float*)d_in[12], (const float*)d_in[13], (const float*)d_in[14],
      (const float*)d_in[15], (const float*)d_in[16], (const float*)d_in[17], (const float*)d_in[18]);
  proj_kernel<<<1024, 512, 0, stream>>>(cat, pwb, (const float*)d_in[20], x,
                                        (float*)d_out);
}